// Round 7
// baseline (301.564 us; speedup 1.0000x reference)
//
#include <hip/hip_runtime.h>
#include <hip/hip_bf16.h>
#include <stdint.h>

// CapsuleLayer dynamic routing, MI355X. fp32 in/out.
// B=256, N=10, I=1152, D=16, K(Din)=8, ROUTINGS=3.
// R12: every kernel sits at ~2.3 TB/s effective while the harness fill hits
//      6.3 -> un-hidden latency, not BW. (a) sweeps: depth-2 rolling register
//      prefetch (rA/rB/rC static rotation) + tree max/sum to shorten the
//      softmax spine. (b) K1: ds_read bank-quad fix for quarter-wave-16
//      processing: stage involution g(row)=(row&3)<<1, read order jj=m^dq
//      -> every 16-lane group covers all 8 bank quads (R11: 1.57M conflicts).
//      Kept: coalesced global_load_lds W staging, XCD swizzle, butterfly.

#define BN 256
#define NN 10
#define II 1152
#define DD 16
#define KK 8
#define NT 18          // K1 i-tiles of 64
#define NP 5           // K1 n-pairs per i-tile
#define NCH 3          // sweep chunks
#define CHI 384        // i per sweep chunk (6 steps of 64)

typedef unsigned short ushort_t;
typedef unsigned int uint_t;

__device__ __forceinline__ float bflo(uint_t u) {
    union { uint_t i; float f; } v; v.i = u << 16; return v.f;
}
__device__ __forceinline__ float bfhi(uint_t u) {
    union { uint_t i; float f; } v; v.i = u & 0xffff0000u; return v.f;
}
// packed f32x2 -> bf16x2 (RTNE) via v_cvt_pk_bf16_f32
__device__ __forceinline__ uint_t pkbf(float lo, float hi) {
    __hip_bfloat162 h = __float22bfloat162_rn(make_float2(lo, hi));
    uint_t u; __builtin_memcpy(&u, &h, sizeof(u)); return u;
}

// ---------------- K1 + sweep0 partials --------------------------------------
// block = (i-tile of 64, n-pair, b-quad). 256 thr = 4 waves.
// lane = il*4+dq: thread owns (i = it*64 + wv*16 + il, d-quad dq), 4 b's,
// 2 consecutive n. XCD-colocation swizzle keeps each XCD's W slice
// L2-resident. Per wave per n, the 8KB W tile (16 rows x 512B) is staged:
//   global_load_lds j=0..7: lane l -> LDS linear l*16+j*1024; source
//   chunk = row*32 + ((l&31) ^ g(row)), row=(l>>5)+2j, g(row)=(row&3)<<1.
//   read instr m: lane (il,dq) reads pos (dq*8+(m^dq))^g(il) -> w[m^dq];
//   bank quad = m ^ dq ^ ((il&3)<<1): all 8 quads per 16-lane group.
// Reduction over il lanes: value-split butterfly (15 shfl per n).
// part0[b][it][n*16+d] = 0.1 * sum_{i in tile} u  (fp32, pre-pack values).
__global__ __launch_bounds__(256) void caps_uhat_s0(const float* __restrict__ xg,
                                                    const float* __restrict__ wg,
                                                    ushort_t* __restrict__ u,
                                                    float* __restrict__ part0,
                                                    int b0, int c4)
{
    __shared__ float wlds[4][2048];     // per-wave 8 KB W stage, 32 KB
    __shared__ float redn[4][64][2];    // [wv][lane][nn], 2 KB
    const int tid = threadIdx.x;
    const int lane = tid & 63, wv = tid >> 6;
    const int dq = lane & 3, il = lane >> 2;
    // grid = 90*c4, c4 multiple of 4 -> divisible by 8
    const int nb8 = gridDim.x >> 3;
    const int L   = (blockIdx.x & 7) * nb8 + (blockIdx.x >> 3);
    const int it  = L / (NP * c4);
    const int rem = L - it * (NP * c4);
    const int np  = rem / c4;
    const int bl  = (rem - np * c4) * 4;       // chunk-local b base (4 b's)
    const int n0  = np * 2;
    const int i = it * 64 + wv * 16 + il;

    const bool h0 = (il & 1), h1 = (il >> 1) & 1, h2 = (il >> 2) & 1, h3 = (il >> 3) & 1;
    float* myred = &redn[wv][lane][0];
    float* mylds = &wlds[wv][0];
    const int lrow = lane >> 5, lc = lane & 31;
    const int gsw = (il & 3) << 1;             // read-side swizzle for this lane's row
    const float4* wtile0 = (const float4*)(wg + (size_t)(n0 * II + it * 64 + wv * 16) * (DD * KK));

#define STAGE_W(NNV)                                                         \
    {                                                                        \
        const float4* wt = wtile0 + (size_t)(NNV) * II * 32;                 \
        _Pragma("unroll")                                                    \
        for (int j = 0; j < 8; ++j) {                                        \
            int row = lrow + 2 * j;                                          \
            int chunk = row * 32 + (lc ^ ((row & 3) << 1));                  \
            __builtin_amdgcn_global_load_lds(                                \
                (const __attribute__((address_space(1))) void*)(wt + chunk), \
                (__attribute__((address_space(3))) void*)(mylds + j * 256),  \
                16, 0, 0);                                                   \
        }                                                                    \
    }

    STAGE_W(0);

    float xv[4][8];
#pragma unroll
    for (int bb = 0; bb < 4; ++bb) {
        const float4* xp = (const float4*)(xg + ((size_t)(b0 + bl + bb) * II + i) * KK);
        float4 x0 = xp[0], x1 = xp[1];
        xv[bb][0] = x0.x; xv[bb][1] = x0.y; xv[bb][2] = x0.z; xv[bb][3] = x0.w;
        xv[bb][4] = x1.x; xv[bb][5] = x1.y; xv[bb][6] = x1.z; xv[bb][7] = x1.w;
    }

    auto compute_n = [&](int n, const float4* w, int slot) {
        float s[4][4];   // [bb][dj], value index j = bb*4+dj
#pragma unroll
        for (int dj = 0; dj < 4; ++dj) {
            float4 wa = w[2 * dj], wb = w[2 * dj + 1];
#pragma unroll
            for (int bb = 0; bb < 4; ++bb) {
                s[bb][dj] = wa.x * xv[bb][0] + wa.y * xv[bb][1]
                          + wa.z * xv[bb][2] + wa.w * xv[bb][3]
                          + wb.x * xv[bb][4] + wb.y * xv[bb][5]
                          + wb.z * xv[bb][6] + wb.w * xv[bb][7];
            }
        }
        // store u (bf16): wave-contiguous 512 B per (b,n)
#pragma unroll
        for (int bb = 0; bb < 4; ++bb) {
            uint2 q;
            q.x = pkbf(s[bb][0], s[bb][1]);
            q.y = pkbf(s[bb][2], s[bb][3]);
            *(uint2*)(u + (((size_t)(bl + bb) * NN + n) * II + i) * DD + dq * 4) = q;
        }
        // value-split butterfly over il lanes (masks 4,8,16,32)
        float v8[8];
#pragma unroll
        for (int k = 0; k < 8; ++k) {
            float a0 = s[(2 * k) >> 2][(2 * k) & 3];
            float a1 = s[(2 * k + 1) >> 2][(2 * k + 1) & 3];
            float give = h0 ? a0 : a1;
            float got  = __shfl_xor(give, 4, 64);
            v8[k] = (h0 ? a1 : a0) + got;
        }
        float v4[4];
#pragma unroll
        for (int k = 0; k < 4; ++k) {
            float a0 = v8[2 * k], a1 = v8[2 * k + 1];
            float give = h1 ? a0 : a1;
            float got  = __shfl_xor(give, 8, 64);
            v4[k] = (h1 ? a1 : a0) + got;
        }
        float v2[2];
#pragma unroll
        for (int k = 0; k < 2; ++k) {
            float a0 = v4[2 * k], a1 = v4[2 * k + 1];
            float give = h2 ? a0 : a1;
            float got  = __shfl_xor(give, 16, 64);
            v2[k] = (h2 ? a1 : a0) + got;
        }
        {
            float a0 = v2[0], a1 = v2[1];
            float give = h3 ? a0 : a1;
            float got  = __shfl_xor(give, 32, 64);
            myred[slot] = (h3 ? a1 : a0) + got;   // ds_write_b32, exclusive slot
        }
    };

    float4 w[8];
    // n0: wait staging (and x), read fragments (swizzled), free buffer, stage n1
    asm volatile("s_waitcnt vmcnt(0)" ::: "memory");
#pragma unroll
    for (int m = 0; m < 8; ++m)
        w[m ^ dq] = *(const float4*)(mylds + il * 128 + (((dq * 8 + (m ^ dq)) ^ gsw) << 2));
    asm volatile("s_waitcnt lgkmcnt(0)" ::: "memory");   // reads done -> buffer free
    STAGE_W(1);
    compute_n(n0, w, 0);

    // n1
    asm volatile("s_waitcnt vmcnt(0)" ::: "memory");
#pragma unroll
    for (int m = 0; m < 8; ++m)
        w[m ^ dq] = *(const float4*)(mylds + il * 128 + (((dq * 8 + (m ^ dq)) ^ gsw) << 2));
    compute_n(n0 + 1, w, 1);
#undef STAGE_W

    __syncthreads();
    if (tid < 128) {
        int bb = tid >> 5, r5 = tid & 31, nn = r5 >> 4, d = r5 & 15;
        int lane2 = ((bb * 4 + (d & 3)) << 2) + (d >> 2);   // il=bb*4+dj, dq=d>>2
        float v = redn[0][lane2][nn] + redn[1][lane2][nn]
                + redn[2][lane2][nn] + redn[3][lane2][nn];
        part0[((size_t)(b0 + bl + bb) * NT + it) * 160 + (n0 + nn) * 16 + d] = 0.1f * v;
    }
}

// ---- block reduction of sp[NN][4] over 64 groups -> 160 floats -------------
__device__ __forceinline__ void block_reduce_part(float sp[NN][4], int tid,
                                                  float* red,
                                                  float* __restrict__ partp)
{
#pragma unroll
    for (int m = 4; m <= 32; m <<= 1)
#pragma unroll
        for (int n = 0; n < NN; ++n)
#pragma unroll
            for (int j = 0; j < 4; ++j)
                sp[n][j] += __shfl_xor(sp[n][j], m, 64);

    const int lane = tid & 63, wv = tid >> 6, ld = tid & 3;
    if (lane < 4) {
#pragma unroll
        for (int n = 0; n < NN; ++n)
#pragma unroll
            for (int j = 0; j < 4; ++j)
                red[(wv * NN + n) * 16 + ld * 4 + j] = sp[n][j];
    }
    __syncthreads();
    if (tid < 160) {
        int n = tid >> 4, dd = tid & 15;
        float v = 0.f;
#pragma unroll
        for (int w = 0; w < 4; ++w) v += red[(w * NN + n) * 16 + dd];
        partp[tid] = v;
    }
}

// ---------------- sweep r=1,2 ----------------------------------------------
// o = squash(sum_{18} part0[b]);  if p1: o += squash(sum_{3} p1[b]).
// c = softmax_n(<o,u>), partial s = sum c*u over this 384-i chunk.
// Depth-2 rolling prefetch: rA/rB/rC rotated by NAME (static indexing only).
__global__ __launch_bounds__(256) void caps_sweep(const ushort_t* __restrict__ u,
                                                  const float* __restrict__ p0,
                                                  const float* __restrict__ p1,
                                                  float* __restrict__ pout, int b0)
{
    __shared__ float red[4 * 160];
    __shared__ float o_s[160];
    const int tid = threadIdx.x, g = tid >> 2, ld = tid & 3;
    const int cb = blockIdx.x / NCH, ch = blockIdx.x % NCH;
    const int b = b0 + cb;
    const ushort_t* ub = u + (size_t)cb * (NN * II * DD);
    const int i0 = ch * CHI + g;

#define ULOAD(R, S)                                                            \
    _Pragma("unroll")                                                          \
    for (int n = 0; n < NN; ++n)                                               \
        R[n] = *(const uint2*)(ub + ((size_t)(n * II + i0 + (S) * 64)) * DD + ld * 4);

    uint2 rA[NN], rB[NN], rC[NN];
    ULOAD(rA, 0)
    ULOAD(rB, 1)

    if (tid < 160) {
        float v = 0.f;
#pragma unroll
        for (int t = 0; t < NT; ++t)
            v += p0[((size_t)b * NT + t) * 160 + tid];
        float sq = v * v;
#pragma unroll
        for (int m = 1; m <= 8; m <<= 1) sq += __shfl_xor(sq, m, 64);
        float o = v * (sqrtf(sq) / (1.0f + sq));
        if (p1) {
            float v1 = 0.f;
#pragma unroll
            for (int c2 = 0; c2 < NCH; ++c2)
                v1 += p1[((size_t)b * NCH + c2) * 160 + tid];
            float sq1 = v1 * v1;
#pragma unroll
            for (int m = 1; m <= 8; m <<= 1) sq1 += __shfl_xor(sq1, m, 64);
            o += v1 * (sqrtf(sq1) / (1.0f + sq1));
        }
        o_s[tid] = o;
    }
    __syncthreads();

    float sp[NN][4];
#pragma unroll
    for (int n = 0; n < NN; ++n)
#pragma unroll
        for (int j = 0; j < 4; ++j) sp[n][j] = 0.f;

#define STEP(R)                                                                \
    {                                                                          \
        float p[NN];                                                           \
        _Pragma("unroll")                                                      \
        for (int n = 0; n < NN; ++n) {                                         \
            float4 o4 = *(const float4*)&o_s[(n << 4) + (ld << 2)];            \
            p[n] = bflo(R[n].x) * o4.x + bfhi(R[n].x) * o4.y                   \
                 + bflo(R[n].y) * o4.z + bfhi(R[n].y) * o4.w;                  \
        }                                                                      \
        float a[NN];                                                           \
        _Pragma("unroll")                                                      \
        for (int n = 0; n < NN; ++n) {                                         \
            float t2 = p[n] + __shfl_xor(p[n], 1, 64);                         \
            a[n] = t2 + __shfl_xor(t2, 2, 64);                                 \
        }                                                                      \
        float m01 = fmaxf(fmaxf(a[0], a[1]), a[2]);                            \
        float m2  = fmaxf(fmaxf(a[3], a[4]), a[5]);                            \
        float m3  = fmaxf(fmaxf(a[6], a[7]), a[8]);                            \
        float mx  = fmaxf(fmaxf(m01, m2), fmaxf(m3, a[9]));                    \
        float c[NN];                                                           \
        _Pragma("unroll")                                                      \
        for (int n = 0; n < NN; ++n) c[n] = __expf(a[n] - mx);                 \
        float s01 = c[0] + c[1], s23 = c[2] + c[3], s45 = c[4] + c[5];         \
        float s67 = c[6] + c[7], s89 = c[8] + c[9];                            \
        float ssum = ((s01 + s23) + (s45 + s67)) + s89;                        \
        float inv = 1.0f / ssum;                                               \
        _Pragma("unroll")                                                      \
        for (int n = 0; n < NN; ++n) {                                         \
            float w = c[n] * inv;                                              \
            sp[n][0] += w * bflo(R[n].x); sp[n][1] += w * bfhi(R[n].x);        \
            sp[n][2] += w * bflo(R[n].y); sp[n][3] += w * bfhi(R[n].y);        \
        }                                                                      \
    }

    ULOAD(rC, 2)  STEP(rA)
    ULOAD(rA, 3)  STEP(rB)
    ULOAD(rB, 4)  STEP(rC)
    ULOAD(rC, 5)  STEP(rA)
    STEP(rB)
    STEP(rC)
#undef ULOAD
#undef STEP

    block_reduce_part(sp, tid, red, pout + ((size_t)b * NCH + ch) * 160);
}

// ---------------- output: squash(sum_ch part2) ------------------------------
__global__ __launch_bounds__(192) void caps_out(const float* __restrict__ p2,
                                                float* __restrict__ out, int b0)
{
    const int b = b0 + blockIdx.x;
    const int t = threadIdx.x;
    if (t < 160) {
        float v = 0.f;
#pragma unroll
        for (int ch = 0; ch < NCH; ++ch)
            v += p2[((size_t)b * NCH + ch) * 160 + t];
        float sq = v * v;
#pragma unroll
        for (int m = 1; m <= 8; m <<= 1) sq += __shfl_xor(sq, m, 64);
        out[(size_t)b * 160 + t] = v * (sqrtf(sq) / (1.0f + sq));
    }
}

extern "C" void kernel_launch(void* const* d_in, const int* in_sizes, int n_in,
                              void* d_out, int out_size, void* d_ws, size_t ws_size,
                              hipStream_t stream)
{
    const float* xg = (const float*)d_in[0];  // [B,I,K]
    const float* wg = (const float*)d_in[1];  // [N,I,D,K]
    if (n_in >= 2 && in_sizes[0] == NN * II * DD * KK) {
        const float* t = xg; xg = wg; wg = t;
    }
    float* outp = (float*)d_out;

    const size_t perB  = (size_t)NN * II * DD * 2;       // 368,640 B bf16 u per b
    const size_t p0B   = (size_t)BN * NT * 160 * 4;      // 2,949,120
    const size_t p12B  = (size_t)BN * NCH * 160 * 4;     // 491,520 each
    size_t extra = p0B + 2 * p12B;
    size_t avail = (ws_size > extra) ? ws_size - extra : 0;
    int C = 256;
    if (avail < (size_t)256 * perB) {
        C = (int)(avail / perB);
        C &= ~15;
        if (C < 16) C = 16;
    }
    ushort_t* uws = (ushort_t*)d_ws;
    float* part0 = (float*)((char*)d_ws + (size_t)C * perB);
    float* part1 = part0 + (size_t)BN * NT * 160;
    float* part2 = part1 + (size_t)BN * NCH * 160;

    for (int b0 = 0; b0 < BN; b0 += C) {
        int c = (BN - b0 < C) ? (BN - b0) : C;
        int c4 = c / 4;
        caps_uhat_s0<<<NT * NP * c4, 256, 0, stream>>>(xg, wg, uws, part0, b0, c4);
        caps_sweep  <<<c * NCH, 256, 0, stream>>>(uws, part0, nullptr, part1, b0);
        caps_sweep  <<<c * NCH, 256, 0, stream>>>(uws, part0, part1,  part2, b0);
        caps_out    <<<c,       192, 0, stream>>>(part2, outp, b0);
    }
}

// Round 8
// 136.618 us; speedup vs baseline: 2.2073x; 2.2073x over previous
//
#include <hip/hip_runtime.h>
#include <hip/hip_bf16.h>
#include <stdint.h>

// CapsuleLayer dynamic routing, MI355X. fp32 in/out.
// B=256, N=10, I=1152, D=16, K(Din)=8, ROUTINGS=3.
// R13: R12's K1 regression was a rule-#20 violation: w[m^dq] (runtime index)
//      demoted the fragment array to scratch (FETCH 9->114MB, WRITE 95->440MB,
//      K1 45->218us). Revert K1 LDS read to R11's static-indexed form
//      (w[jj], stage swizzle lc^(row&7)). Bank-conflict theory dead: counts
//      identical across swizzles (272 cyc/block, noise).
//      KEEP from R12: sweep depth-2 rolling prefetch + tree max/sum
//      (non-K1 time 96 -> 83us).

#define BN 256
#define NN 10
#define II 1152
#define DD 16
#define KK 8
#define NT 18          // K1 i-tiles of 64
#define NP 5           // K1 n-pairs per i-tile
#define NCH 3          // sweep chunks
#define CHI 384        // i per sweep chunk (6 steps of 64)

typedef unsigned short ushort_t;
typedef unsigned int uint_t;

__device__ __forceinline__ float bflo(uint_t u) {
    union { uint_t i; float f; } v; v.i = u << 16; return v.f;
}
__device__ __forceinline__ float bfhi(uint_t u) {
    union { uint_t i; float f; } v; v.i = u & 0xffff0000u; return v.f;
}
// packed f32x2 -> bf16x2 (RTNE) via v_cvt_pk_bf16_f32
__device__ __forceinline__ uint_t pkbf(float lo, float hi) {
    __hip_bfloat162 h = __float22bfloat162_rn(make_float2(lo, hi));
    uint_t u; __builtin_memcpy(&u, &h, sizeof(u)); return u;
}

// ---------------- K1 + sweep0 partials --------------------------------------
// block = (i-tile of 64, n-pair, b-quad). 256 thr = 4 waves.
// lane = il*4+dq: thread owns (i = it*64 + wv*16 + il, d-quad dq), 4 b's,
// 2 consecutive n. XCD-colocation swizzle keeps each XCD's W slice
// L2-resident. Per wave per n, the 8KB W tile (16 rows x 512B) is staged:
//   global_load_lds j=0..7: lane l writes LDS linear l*16+j*1024; source
//   chunk = row*32 + ((l&31) ^ (row&7)), row = (l>>5)+2j  [XOR involution]
//   ds_read: lane (il,dq) frag jj at float idx il*128+dq*32+((jj^(il&7))<<2)
//   (jj is COMPILE-TIME: w[jj] static -> stays in VGPRs; rule #20)
// Reduction over il lanes: value-split butterfly (15 shfl per n).
// part0[b][it][n*16+d] = 0.1 * sum_{i in tile} u  (fp32, pre-pack values).
__global__ __launch_bounds__(256) void caps_uhat_s0(const float* __restrict__ xg,
                                                    const float* __restrict__ wg,
                                                    ushort_t* __restrict__ u,
                                                    float* __restrict__ part0,
                                                    int b0, int c4)
{
    __shared__ float wlds[4][2048];     // per-wave 8 KB W stage, 32 KB
    __shared__ float redn[4][64][2];    // [wv][lane][nn], 2 KB
    const int tid = threadIdx.x;
    const int lane = tid & 63, wv = tid >> 6;
    const int dq = lane & 3, il = lane >> 2;
    // grid = 90*c4, c4 multiple of 4 -> divisible by 8
    const int nb8 = gridDim.x >> 3;
    const int L   = (blockIdx.x & 7) * nb8 + (blockIdx.x >> 3);
    const int it  = L / (NP * c4);
    const int rem = L - it * (NP * c4);
    const int np  = rem / c4;
    const int bl  = (rem - np * c4) * 4;       // chunk-local b base (4 b's)
    const int n0  = np * 2;
    const int i = it * 64 + wv * 16 + il;

    const bool h0 = (il & 1), h1 = (il >> 1) & 1, h2 = (il >> 2) & 1, h3 = (il >> 3) & 1;
    float* myred = &redn[wv][lane][0];
    float* mylds = &wlds[wv][0];
    const int lrow = lane >> 5, lc = lane & 31;
    const float4* wtile0 = (const float4*)(wg + (size_t)(n0 * II + it * 64 + wv * 16) * (DD * KK));

#define STAGE_W(NNV)                                                         \
    {                                                                        \
        const float4* wt = wtile0 + (size_t)(NNV) * II * 32;                 \
        _Pragma("unroll")                                                    \
        for (int j = 0; j < 8; ++j) {                                        \
            int row = lrow + 2 * j;                                          \
            int chunk = row * 32 + (lc ^ (row & 7));                         \
            __builtin_amdgcn_global_load_lds(                                \
                (const __attribute__((address_space(1))) void*)(wt + chunk), \
                (__attribute__((address_space(3))) void*)(mylds + j * 256),  \
                16, 0, 0);                                                   \
        }                                                                    \
    }

    STAGE_W(0);

    float xv[4][8];
#pragma unroll
    for (int bb = 0; bb < 4; ++bb) {
        const float4* xp = (const float4*)(xg + ((size_t)(b0 + bl + bb) * II + i) * KK);
        float4 x0 = xp[0], x1 = xp[1];
        xv[bb][0] = x0.x; xv[bb][1] = x0.y; xv[bb][2] = x0.z; xv[bb][3] = x0.w;
        xv[bb][4] = x1.x; xv[bb][5] = x1.y; xv[bb][6] = x1.z; xv[bb][7] = x1.w;
    }

    auto compute_n = [&](int n, const float4* w, int slot) {
        float s[4][4];   // [bb][dj], value index j = bb*4+dj
#pragma unroll
        for (int dj = 0; dj < 4; ++dj) {
            float4 wa = w[2 * dj], wb = w[2 * dj + 1];
#pragma unroll
            for (int bb = 0; bb < 4; ++bb) {
                s[bb][dj] = wa.x * xv[bb][0] + wa.y * xv[bb][1]
                          + wa.z * xv[bb][2] + wa.w * xv[bb][3]
                          + wb.x * xv[bb][4] + wb.y * xv[bb][5]
                          + wb.z * xv[bb][6] + wb.w * xv[bb][7];
            }
        }
        // store u (bf16): wave-contiguous 512 B per (b,n)
#pragma unroll
        for (int bb = 0; bb < 4; ++bb) {
            uint2 q;
            q.x = pkbf(s[bb][0], s[bb][1]);
            q.y = pkbf(s[bb][2], s[bb][3]);
            *(uint2*)(u + (((size_t)(bl + bb) * NN + n) * II + i) * DD + dq * 4) = q;
        }
        // value-split butterfly over il lanes (masks 4,8,16,32)
        float v8[8];
#pragma unroll
        for (int k = 0; k < 8; ++k) {
            float a0 = s[(2 * k) >> 2][(2 * k) & 3];
            float a1 = s[(2 * k + 1) >> 2][(2 * k + 1) & 3];
            float give = h0 ? a0 : a1;
            float got  = __shfl_xor(give, 4, 64);
            v8[k] = (h0 ? a1 : a0) + got;
        }
        float v4[4];
#pragma unroll
        for (int k = 0; k < 4; ++k) {
            float a0 = v8[2 * k], a1 = v8[2 * k + 1];
            float give = h1 ? a0 : a1;
            float got  = __shfl_xor(give, 8, 64);
            v4[k] = (h1 ? a1 : a0) + got;
        }
        float v2[2];
#pragma unroll
        for (int k = 0; k < 2; ++k) {
            float a0 = v4[2 * k], a1 = v4[2 * k + 1];
            float give = h2 ? a0 : a1;
            float got  = __shfl_xor(give, 16, 64);
            v2[k] = (h2 ? a1 : a0) + got;
        }
        {
            float a0 = v2[0], a1 = v2[1];
            float give = h3 ? a0 : a1;
            float got  = __shfl_xor(give, 32, 64);
            myred[slot] = (h3 ? a1 : a0) + got;   // ds_write_b32, exclusive slot
        }
    };

    float4 w[8];
    // n0: wait staging (and x), read fragments (swizzled), free buffer, stage n1
    asm volatile("s_waitcnt vmcnt(0)" ::: "memory");
#pragma unroll
    for (int jj = 0; jj < 8; ++jj)
        w[jj] = *(const float4*)(mylds + il * 128 + dq * 32 + ((jj ^ (il & 7)) << 2));
    asm volatile("s_waitcnt lgkmcnt(0)" ::: "memory");   // reads done -> buffer free
    STAGE_W(1);
    compute_n(n0, w, 0);

    // n1
    asm volatile("s_waitcnt vmcnt(0)" ::: "memory");
#pragma unroll
    for (int jj = 0; jj < 8; ++jj)
        w[jj] = *(const float4*)(mylds + il * 128 + dq * 32 + ((jj ^ (il & 7)) << 2));
    compute_n(n0 + 1, w, 1);
#undef STAGE_W

    __syncthreads();
    if (tid < 128) {
        int bb = tid >> 5, r5 = tid & 31, nn = r5 >> 4, d = r5 & 15;
        int lane2 = ((bb * 4 + (d & 3)) << 2) + (d >> 2);   // il=bb*4+dj, dq=d>>2
        float v = redn[0][lane2][nn] + redn[1][lane2][nn]
                + redn[2][lane2][nn] + redn[3][lane2][nn];
        part0[((size_t)(b0 + bl + bb) * NT + it) * 160 + (n0 + nn) * 16 + d] = 0.1f * v;
    }
}

// ---- block reduction of sp[NN][4] over 64 groups -> 160 floats -------------
__device__ __forceinline__ void block_reduce_part(float sp[NN][4], int tid,
                                                  float* red,
                                                  float* __restrict__ partp)
{
#pragma unroll
    for (int m = 4; m <= 32; m <<= 1)
#pragma unroll
        for (int n = 0; n < NN; ++n)
#pragma unroll
            for (int j = 0; j < 4; ++j)
                sp[n][j] += __shfl_xor(sp[n][j], m, 64);

    const int lane = tid & 63, wv = tid >> 6, ld = tid & 3;
    if (lane < 4) {
#pragma unroll
        for (int n = 0; n < NN; ++n)
#pragma unroll
            for (int j = 0; j < 4; ++j)
                red[(wv * NN + n) * 16 + ld * 4 + j] = sp[n][j];
    }
    __syncthreads();
    if (tid < 160) {
        int n = tid >> 4, dd = tid & 15;
        float v = 0.f;
#pragma unroll
        for (int w = 0; w < 4; ++w) v += red[(w * NN + n) * 16 + dd];
        partp[tid] = v;
    }
}

// ---------------- sweep r=1,2 ----------------------------------------------
// o = squash(sum_{18} part0[b]);  if p1: o += squash(sum_{3} p1[b]).
// c = softmax_n(<o,u>), partial s = sum c*u over this 384-i chunk.
// Depth-2 rolling prefetch: rA/rB/rC rotated by NAME (static indexing only).
__global__ __launch_bounds__(256) void caps_sweep(const ushort_t* __restrict__ u,
                                                  const float* __restrict__ p0,
                                                  const float* __restrict__ p1,
                                                  float* __restrict__ pout, int b0)
{
    __shared__ float red[4 * 160];
    __shared__ float o_s[160];
    const int tid = threadIdx.x, g = tid >> 2, ld = tid & 3;
    const int cb = blockIdx.x / NCH, ch = blockIdx.x % NCH;
    const int b = b0 + cb;
    const ushort_t* ub = u + (size_t)cb * (NN * II * DD);
    const int i0 = ch * CHI + g;

#define ULOAD(R, S)                                                            \
    _Pragma("unroll")                                                          \
    for (int n = 0; n < NN; ++n)                                               \
        R[n] = *(const uint2*)(ub + ((size_t)(n * II + i0 + (S) * 64)) * DD + ld * 4);

    uint2 rA[NN], rB[NN], rC[NN];
    ULOAD(rA, 0)
    ULOAD(rB, 1)

    if (tid < 160) {
        float v = 0.f;
#pragma unroll
        for (int t = 0; t < NT; ++t)
            v += p0[((size_t)b * NT + t) * 160 + tid];
        float sq = v * v;
#pragma unroll
        for (int m = 1; m <= 8; m <<= 1) sq += __shfl_xor(sq, m, 64);
        float o = v * (sqrtf(sq) / (1.0f + sq));
        if (p1) {
            float v1 = 0.f;
#pragma unroll
            for (int c2 = 0; c2 < NCH; ++c2)
                v1 += p1[((size_t)b * NCH + c2) * 160 + tid];
            float sq1 = v1 * v1;
#pragma unroll
            for (int m = 1; m <= 8; m <<= 1) sq1 += __shfl_xor(sq1, m, 64);
            o += v1 * (sqrtf(sq1) / (1.0f + sq1));
        }
        o_s[tid] = o;
    }
    __syncthreads();

    float sp[NN][4];
#pragma unroll
    for (int n = 0; n < NN; ++n)
#pragma unroll
        for (int j = 0; j < 4; ++j) sp[n][j] = 0.f;

#define STEP(R)                                                                \
    {                                                                          \
        float p[NN];                                                           \
        _Pragma("unroll")                                                      \
        for (int n = 0; n < NN; ++n) {                                         \
            float4 o4 = *(const float4*)&o_s[(n << 4) + (ld << 2)];            \
            p[n] = bflo(R[n].x) * o4.x + bfhi(R[n].x) * o4.y                   \
                 + bflo(R[n].y) * o4.z + bfhi(R[n].y) * o4.w;                  \
        }                                                                      \
        float a[NN];                                                           \
        _Pragma("unroll")                                                      \
        for (int n = 0; n < NN; ++n) {                                         \
            float t2 = p[n] + __shfl_xor(p[n], 1, 64);                         \
            a[n] = t2 + __shfl_xor(t2, 2, 64);                                 \
        }                                                                      \
        float m01 = fmaxf(fmaxf(a[0], a[1]), a[2]);                            \
        float m2  = fmaxf(fmaxf(a[3], a[4]), a[5]);                            \
        float m3  = fmaxf(fmaxf(a[6], a[7]), a[8]);                            \
        float mx  = fmaxf(fmaxf(m01, m2), fmaxf(m3, a[9]));                    \
        float c[NN];                                                           \
        _Pragma("unroll")                                                      \
        for (int n = 0; n < NN; ++n) c[n] = __expf(a[n] - mx);                 \
        float s01 = c[0] + c[1], s23 = c[2] + c[3], s45 = c[4] + c[5];         \
        float s67 = c[6] + c[7], s89 = c[8] + c[9];                            \
        float ssum = ((s01 + s23) + (s45 + s67)) + s89;                        \
        float inv = 1.0f / ssum;                                               \
        _Pragma("unroll")                                                      \
        for (int n = 0; n < NN; ++n) {                                         \
            float w = c[n] * inv;                                              \
            sp[n][0] += w * bflo(R[n].x); sp[n][1] += w * bfhi(R[n].x);        \
            sp[n][2] += w * bflo(R[n].y); sp[n][3] += w * bfhi(R[n].y);        \
        }                                                                      \
    }

    ULOAD(rC, 2)  STEP(rA)
    ULOAD(rA, 3)  STEP(rB)
    ULOAD(rB, 4)  STEP(rC)
    ULOAD(rC, 5)  STEP(rA)
    STEP(rB)
    STEP(rC)
#undef ULOAD
#undef STEP

    block_reduce_part(sp, tid, red, pout + ((size_t)b * NCH + ch) * 160);
}

// ---------------- output: squash(sum_ch part2) ------------------------------
__global__ __launch_bounds__(192) void caps_out(const float* __restrict__ p2,
                                                float* __restrict__ out, int b0)
{
    const int b = b0 + blockIdx.x;
    const int t = threadIdx.x;
    if (t < 160) {
        float v = 0.f;
#pragma unroll
        for (int ch = 0; ch < NCH; ++ch)
            v += p2[((size_t)b * NCH + ch) * 160 + t];
        float sq = v * v;
#pragma unroll
        for (int m = 1; m <= 8; m <<= 1) sq += __shfl_xor(sq, m, 64);
        out[(size_t)b * 160 + t] = v * (sqrtf(sq) / (1.0f + sq));
    }
}

extern "C" void kernel_launch(void* const* d_in, const int* in_sizes, int n_in,
                              void* d_out, int out_size, void* d_ws, size_t ws_size,
                              hipStream_t stream)
{
    const float* xg = (const float*)d_in[0];  // [B,I,K]
    const float* wg = (const float*)d_in[1];  // [N,I,D,K]
    if (n_in >= 2 && in_sizes[0] == NN * II * DD * KK) {
        const float* t = xg; xg = wg; wg = t;
    }
    float* outp = (float*)d_out;

    const size_t perB  = (size_t)NN * II * DD * 2;       // 368,640 B bf16 u per b
    const size_t p0B   = (size_t)BN * NT * 160 * 4;      // 2,949,120
    const size_t p12B  = (size_t)BN * NCH * 160 * 4;     // 491,520 each
    size_t extra = p0B + 2 * p12B;
    size_t avail = (ws_size > extra) ? ws_size - extra : 0;
    int C = 256;
    if (avail < (size_t)256 * perB) {
        C = (int)(avail / perB);
        C &= ~15;
        if (C < 16) C = 16;
    }
    ushort_t* uws = (ushort_t*)d_ws;
    float* part0 = (float*)((char*)d_ws + (size_t)C * perB);
    float* part1 = part0 + (size_t)BN * NT * 160;
    float* part2 = part1 + (size_t)BN * NCH * 160;

    for (int b0 = 0; b0 < BN; b0 += C) {
        int c = (BN - b0 < C) ? (BN - b0) : C;
        int c4 = c / 4;
        caps_uhat_s0<<<NT * NP * c4, 256, 0, stream>>>(xg, wg, uws, part0, b0, c4);
        caps_sweep  <<<c * NCH, 256, 0, stream>>>(uws, part0, nullptr, part1, b0);
        caps_sweep  <<<c * NCH, 256, 0, stream>>>(uws, part0, part1,  part2, b0);
        caps_out    <<<c,       192, 0, stream>>>(part2, outp, b0);
    }
}